// Round 10
// baseline (415.908 us; speedup 1.0000x reference)
//
#include <hip/hip_runtime.h>
#include <hip/hip_bf16.h>
#include <math.h>

#define BB 4
#define NQ 1024
#define NKV 4096
#define DMODEL 1024
#define NH 16
#define HD 64

typedef __attribute__((ext_vector_type(8))) short short8;
typedef __attribute__((ext_vector_type(4))) float floatx4;

__device__ __forceinline__ unsigned short f2bf(float f) {
    __hip_bfloat16 b = __float2bfloat16(f);
    return *reinterpret_cast<unsigned short*>(&b);
}

// pack two known-finite positive floats to bf16x2, round-half-up (proven v4-v11)
__device__ __forceinline__ unsigned int pack2bf_rhu(float a, float b) {
    unsigned ua = __builtin_bit_cast(unsigned, a) + 0x8000u;
    unsigned ub = __builtin_bit_cast(unsigned, b) + 0x8000u;
    return (ua >> 16) | (ub & 0xffff0000u);
}

// async global->LDS DMA, 16B/lane. Dest = wave-uniform base + lane*16.
__device__ __forceinline__ void gl_lds16(void* lds, const void* g) {
    __builtin_amdgcn_global_load_lds(
        (const __attribute__((address_space(1))) unsigned int*)g,
        (__attribute__((address_space(3))) unsigned int*)lds, 16, 0, 0);
}

// ---------------- mask: detect format + expand to AND-halfwords ----------------
// output: 0xFFFF = keep, 0x0000 = masked (applied by AND on packed bf16 P)
__global__ __launch_bounds__(1024) void maskprep3(const int* __restrict__ mask,
                                                  unsigned short* __restrict__ maskb) {
    __shared__ int s;
    if (threadIdx.x == 0) s = 0;
    __syncthreads();
    int local = 0;
    for (int i = threadIdx.x; i < 4096; i += 1024)
        if (((const unsigned*)mask)[i] > 1u) local = 1;
    if (local) atomicOr(&s, 1);
    __syncthreads();
    const bool bytes = (s != 0);
    for (int i = threadIdx.x; i < BB * NKV; i += 1024) {
        bool m = bytes ? (((const unsigned char*)mask)[i] != 0) : (mask[i] != 0);
        maskb[i] = m ? (unsigned short)0 : (unsigned short)0xFFFFu;
    }
}

// ---------------- all 3 weight transposes in ONE launch -------------------------
__global__ __launch_bounds__(256) void transpose_cast3(
    const float* __restrict__ Wq, const float* __restrict__ Wkv,
    const float* __restrict__ Wproj,
    unsigned short* __restrict__ WqT, unsigned short* __restrict__ WkvT,
    unsigned short* __restrict__ WprojT)
{
    const float* src; unsigned short* dst; int N;
    if (blockIdx.z == 0)      { src = Wq;    dst = WqT;    N = DMODEL; }
    else if (blockIdx.z == 1) { src = Wkv;   dst = WkvT;   N = 2 * DMODEL; }
    else                      { src = Wproj; dst = WprojT; N = DMODEL; }
    if ((int)blockIdx.x * 64 >= N) return;
    const int K = DMODEL;
    __shared__ unsigned short t[64][72];
    int r0 = blockIdx.y * 64, c0 = blockIdx.x * 64;
    int tid = threadIdx.x;
#pragma unroll
    for (int i = 0; i < 4; i++) {
        int r = i * 16 + (tid >> 4), c = (tid & 15) * 4;
        float4 v = *(const float4*)&src[(size_t)(r0 + r) * N + c0 + c];
        t[c + 0][r] = f2bf(v.x); t[c + 1][r] = f2bf(v.y);
        t[c + 2][r] = f2bf(v.z); t[c + 3][r] = f2bf(v.w);
    }
    __syncthreads();
#pragma unroll
    for (int i = 0; i < 2; i++) {
        int rr = i * 32 + (tid >> 3), cc = (tid & 7) * 8;
        *(uint4*)&dst[(size_t)(c0 + rr) * K + r0 + cc] = *(uint4*)&t[rr][cc];
    }
}

// ---------------- bf16 MFMA GEMM: C = alpha * A @ Bt^T (proven R3) ----------------
// R8: AF32 template arg — when 1, A is staged fp32->regs->f2bf->ds_write at
// the BYTE-IDENTICAL swizzled LDS location gl_lds16 used (same rounding as
// the removed cast_bf16 => bit-identical results). Kills the standalone cast
// kernels + d_out staging + the serialized kv-proj halves. Also bijective
// XCD swizzle on the grid (nwg % 8 == 0 for all launches; perf-only).
template <int EPI, int AF32>
__global__ __launch_bounds__(256) void gemm_mfma(
    const unsigned short* __restrict__ A,
    const float* __restrict__ A32,
    const unsigned short* __restrict__ Bt,
    const float* __restrict__ bias,
    unsigned short* __restrict__ o16,
    unsigned short* __restrict__ oT,
    float* __restrict__ o32,
    int M, int N, int K, float alpha, int m_out_base)
{
    extern __shared__ char smem[];
    unsigned short* As = (unsigned short*)smem;            // 512 chunks = 8KB
    unsigned short* Bs = (unsigned short*)(smem + 8192);   // 512 chunks = 8KB
    const int tid = threadIdx.x;
    const int wave = tid >> 6, lane = tid & 63;
    const int quad = lane >> 4, l16 = lane & 15;
    const int wm = wave >> 1, wn = wave & 1;

    // bijective XCD swizzle (nwg % 8 == 0 for all our grids)
    const int nwg = gridDim.x * gridDim.y;
    const int lid0 = blockIdx.y * gridDim.x + blockIdx.x;
    const int lid = (lid0 & 7) * (nwg >> 3) + (lid0 >> 3);
    const int bx = lid % gridDim.x, by = lid / gridDim.x;
    const int m0 = by * 128, n0 = bx * 128;

    const int c0 = wave * 64 + lane, c1 = c0 + 256;
    const int r0s = c0 >> 2, cc0 = (c0 & 3) ^ ((r0s >> 2) & 3);
    const int r1s = c1 >> 2, cc1 = (c1 & 3) ^ ((r1s >> 2) & 3);
    const unsigned short* bg0 = Bt + (size_t)(n0 + r0s) * K + cc0 * 8;
    const unsigned short* bg1 = Bt + (size_t)(n0 + r1s) * K + cc1 * 8;
    char* AldsW0 = (char*)As + (wave * 64) * 16;
    char* AldsW1 = (char*)As + (256 + wave * 64) * 16;
    char* BldsW0 = (char*)Bs + (wave * 64) * 16;
    char* BldsW1 = (char*)Bs + (256 + wave * 64) * 16;
    char* Alane0 = (char*)As + c0 * 16;   // per-lane A dest (AF32 path)
    char* Alane1 = (char*)As + c1 * 16;

    const unsigned short* ag0 = nullptr; const unsigned short* ag1 = nullptr;
    const float* ag0f = nullptr; const float* ag1f = nullptr;
    if constexpr (AF32) {
        ag0f = A32 + (size_t)(m0 + r0s) * K + cc0 * 8;
        ag1f = A32 + (size_t)(m0 + r1s) * K + cc1 * 8;
    } else {
        ag0 = A + (size_t)(m0 + r0s) * K + cc0 * 8;
        ag1 = A + (size_t)(m0 + r1s) * K + cc1 * 8;
    }

    int achk[4], bchk[4];
#pragma unroll
    for (int i = 0; i < 4; i++) {
        int ra = wm * 64 + i * 16 + l16;
        achk[i] = ra * 4 + (quad ^ ((ra >> 2) & 3));
        int rb = wn * 64 + i * 16 + l16;
        bchk[i] = rb * 4 + (quad ^ ((rb >> 2) & 3));
    }

    floatx4 acc[4][4];
#pragma unroll
    for (int i = 0; i < 4; i++)
#pragma unroll
        for (int j = 0; j < 4; j++) acc[i][j] = (floatx4)0.0f;

    for (int kt = 0; kt < K; kt += 32) {
        __syncthreads();
        if constexpr (AF32) {
            float4 x0 = *(const float4*)(ag0f + kt);
            float4 x1 = *(const float4*)(ag0f + kt + 4);
            float4 x2 = *(const float4*)(ag1f + kt);
            float4 x3 = *(const float4*)(ag1f + kt + 4);
            gl_lds16(BldsW0, bg0 + kt);
            gl_lds16(BldsW1, bg1 + kt);
            short8 v0, v1;
            v0[0] = (short)f2bf(x0.x); v0[1] = (short)f2bf(x0.y);
            v0[2] = (short)f2bf(x0.z); v0[3] = (short)f2bf(x0.w);
            v0[4] = (short)f2bf(x1.x); v0[5] = (short)f2bf(x1.y);
            v0[6] = (short)f2bf(x1.z); v0[7] = (short)f2bf(x1.w);
            v1[0] = (short)f2bf(x2.x); v1[1] = (short)f2bf(x2.y);
            v1[2] = (short)f2bf(x2.z); v1[3] = (short)f2bf(x2.w);
            v1[4] = (short)f2bf(x3.x); v1[5] = (short)f2bf(x3.y);
            v1[6] = (short)f2bf(x3.z); v1[7] = (short)f2bf(x3.w);
            *(short8*)Alane0 = v0;
            *(short8*)Alane1 = v1;
        } else {
            gl_lds16(AldsW0, ag0 + kt);
            gl_lds16(AldsW1, ag1 + kt);
            gl_lds16(BldsW0, bg0 + kt);
            gl_lds16(BldsW1, bg1 + kt);
        }
        __syncthreads();
        short8 af[4], bfr[4];
#pragma unroll
        for (int i = 0; i < 4; i++) af[i] = *(const short8*)&As[achk[i] * 8];
#pragma unroll
        for (int j = 0; j < 4; j++) bfr[j] = *(const short8*)&Bs[bchk[j] * 8];
#pragma unroll
        for (int i = 0; i < 4; i++)
#pragma unroll
            for (int j = 0; j < 4; j++)
                acc[i][j] = __builtin_amdgcn_mfma_f32_16x16x32_bf16(
                    af[i], bfr[j], acc[i][j], 0, 0, 0);
    }

    const int rowbase = m0 + wm * 64;
    const int colbase = n0 + wn * 64;
    if (EPI == 0) {
#pragma unroll
        for (int i = 0; i < 4; i++)
#pragma unroll
            for (int r = 0; r < 4; r++) {
                size_t row = (size_t)(rowbase + i * 16 + quad * 4 + r);
#pragma unroll
                for (int j = 0; j < 4; j++)
                    o16[row * N + colbase + j * 16 + l16] =
                        f2bf(acc[i][j][r] * alpha);
            }
    } else if (EPI == 2) {
        float bv[4];
#pragma unroll
        for (int j = 0; j < 4; j++) bv[j] = bias[colbase + j * 16 + l16];
#pragma unroll
        for (int i = 0; i < 4; i++)
#pragma unroll
            for (int r = 0; r < 4; r++) {
                size_t row = (size_t)(rowbase + i * 16 + quad * 4 + r);
#pragma unroll
                for (int j = 0; j < 4; j++)
                    o32[row * N + colbase + j * 16 + l16] = acc[i][j][r] + bv[j];
            }
    } else {  // EPI == 1: N=2048; cols<1024 -> Kb natural, cols>=1024 -> VTb^T
        if (n0 < DMODEL) {
#pragma unroll
            for (int i = 0; i < 4; i++)
#pragma unroll
                for (int r = 0; r < 4; r++) {
                    int gm = m_out_base + rowbase + i * 16 + quad * 4 + r;
                    int b = gm >> 12, key = gm & (NKV - 1);
                    size_t row = (size_t)(b * NKV + key);
#pragma unroll
                    for (int j = 0; j < 4; j++)
                        o16[row * DMODEL + colbase + j * 16 + l16] =
                            f2bf(acc[i][j][r]);
                }
        } else {
            __syncthreads();
            unsigned short (*scr)[72] =
                (unsigned short(*)[72])(smem + wave * 64 * 72 * 2);
#pragma unroll
            for (int i = 0; i < 4; i++)
#pragma unroll
                for (int j = 0; j < 4; j++)
#pragma unroll
                    for (int r = 0; r < 4; r++)
                        scr[j * 16 + l16][i * 16 + quad * 4 + r] =
                            f2bf(acc[i][j][r]);
            __syncthreads();
            int gmb = m_out_base + rowbase;
            int b = gmb >> 12, key0 = gmb & (NKV - 1);
            int d0 = colbase - DMODEL;
#pragma unroll
            for (int p = 0; p < 8; p++) {
                int rr = p * 8 + (lane >> 3), ch = lane & 7;
                *(uint4*)&oT[((size_t)(b * DMODEL + d0 + rr)) * NKV + key0 + ch * 8] =
                    *(uint4*)&scr[rr][ch * 8];
            }
        }
    }
}

// ---------------- fused flash attention v11: KV-split, register-lean ------------
// (unchanged from R7 — PASS @ 102.7us; LDS-pipe-bound incl. conflicts;
//  accumulators in AGPRs, VGPR=64, no spill)
__global__ __launch_bounds__(512, 2) void attn_mfma11(
    const unsigned short* __restrict__ Qb,   // (B,NQ,D) bf16, scaled
    const unsigned short* __restrict__ Kb,   // (B,NKV,D) bf16
    const unsigned short* __restrict__ VTb,  // (B,D,NKV) bf16
    const unsigned short* __restrict__ maskb,// (B,NKV) 0xFFFF keep / 0 masked
    unsigned short* __restrict__ x)          // (B,NQ,D) bf16
{
    const int lid = blockIdx.y * gridDim.x + blockIdx.x;  // [0,512)
    const int xcd = lid & 7, slot = lid >> 3;             // slot in [0,64)
    const int bh = xcd * 8 + (slot & 7);    // 8 q-tiles of one (b,h) per XCD
    const int b = bh >> 4, h = bh & 15;
    const int m0 = (slot >> 3) * 128;
    const int tid = threadIdx.x;
    const int wave = tid >> 6, lane = tid & 63;
    const int quad = lane >> 4, l16 = lane & 15;
    const int sp = wave & 3;   // strip-pair: rows m0+sp*32 .. +32
    const int g  = wave >> 2;  // KV half: tiles g*32 .. g*32+31

    __shared__ __align__(16) char smem[55296];
    unsigned short (*k_s)[64][72]  = (unsigned short (*)[64][72])(smem);          // [2]
    unsigned short (*vT_s)[64][72] = (unsigned short (*)[64][72])(smem + 18432);  // [2]
    unsigned short (*qp_s)[16][72] = (unsigned short (*)[16][72])(smem + 36864);  // [8]
    float* comb = (float*)smem;  // epilogue reuse: 256 lanes x 40 floats = 40KB

    const unsigned short* Kbase = Kb + ((size_t)b * NKV) * DMODEL + h * HD;
    const unsigned short* Vbase = VTb + ((size_t)(b * DMODEL + h * HD)) * NKV;

    // staging: 256-thread group sg stages stream sg; 2 uint4 per array/thread
    const int sg  = tid >> 8;           // 0/1 = which stream this thread stages
    const int t8  = tid & 255;
    const int sr  = t8 >> 2;            // row 0..63
    const int sc  = (t8 & 3) * 16;      // col 0,16,32,48
    const int key00 = sg * 2048;        // stream's first key

    // prologue: stage tile (sg*32) of each stream
    {
        const unsigned short* ks = Kbase + (size_t)(key00 + sr) * DMODEL + sc;
        uint4 a0 = *(const uint4*)ks, a1 = *(const uint4*)(ks + 8);
        const unsigned short* vs = Vbase + (size_t)sr * NKV + key00 + sc;
        uint4 b0 = *(const uint4*)vs, b1 = *(const uint4*)(vs + 8);
        *(uint4*)&k_s[sg][sr][sc]      = a0;
        *(uint4*)&k_s[sg][sr][sc + 8]  = a1;
        *(uint4*)&vT_s[sg][sr][sc]     = b0;
        *(uint4*)&vT_s[sg][sr][sc + 8] = b1;
    }

    // Q B-frags for both strips of this wave's pair (direct from global)
    short8 bq[2][2];
#pragma unroll
    for (int s = 0; s < 2; s++) {
        const unsigned short* qsrc =
            Qb + ((size_t)(b * NQ + m0 + sp * 32 + s * 16 + l16)) * DMODEL +
            h * HD + quad * 8;
        bq[s][0] = *(const short8*)qsrc;
        bq[s][1] = *(const short8*)(qsrc + 32);
    }

    const unsigned short* mrow = maskb + b * NKV + g * 2048;
    unsigned short* prow = &qp_s[wave][l16][0];

    short8 ones;
#pragma unroll
    for (int e = 0; e < 8; e++) ones[e] = (short)0x3F80;  // bf16 1.0

    floatx4 o[2][4], ol[2];
#pragma unroll
    for (int s = 0; s < 2; s++) {
#pragma unroll
        for (int f = 0; f < 4; f++) o[s][f] = (floatx4)0.0f;
        ol[s] = (floatx4)0.0f;
    }

    __syncthreads();  // prologue staging visible

    for (int i = 0; i < 32; i++) {
        if (i) __syncthreads();  // commits from prev iter visible
        const bool pf = (i < 31);
        const int nn = key00 + (i + 1) * 64;

        // K prefetch issued before QK (8 VGPRs live through QK phase)
        uint4 pk0, pk1;
        if (pf) {
            const unsigned short* ks = Kbase + (size_t)(nn + sr) * DMODEL + sc;
            pk0 = *(const uint4*)ks; pk1 = *(const uint4*)(ks + 8);
        }

        // QK: f-loop, ak[f] read ONCE and shared by both strips
        floatx4 st[2][4];
        __builtin_amdgcn_s_setprio(1);
#pragma unroll
        for (int f = 0; f < 4; f++) {
            short8 ak0 = *(const short8*)&k_s[g][f * 16 + l16][quad * 8];
            short8 ak1 = *(const short8*)&k_s[g][f * 16 + l16][32 + quad * 8];
            floatx4 t0 = (floatx4)0.0f, t1 = (floatx4)0.0f;
            t0 = __builtin_amdgcn_mfma_f32_16x16x32_bf16(ak0, bq[0][0], t0, 0, 0, 0);
            t0 = __builtin_amdgcn_mfma_f32_16x16x32_bf16(ak1, bq[0][1], t0, 0, 0, 0);
            t1 = __builtin_amdgcn_mfma_f32_16x16x32_bf16(ak0, bq[1][0], t1, 0, 0, 0);
            t1 = __builtin_amdgcn_mfma_f32_16x16x32_bf16(ak1, bq[1][1], t1, 0, 0, 0);
            st[0][f] = t0; st[1][f] = t1;
        }
        __builtin_amdgcn_s_setprio(0);

        // V prefetch issued after QK (8 VGPRs live through softmax+PV)
        uint4 pv0, pv1;
        if (pf) {
            const unsigned short* vs = Vbase + (size_t)sr * NKV + nn + sc;
            pv0 = *(const uint4*)vs; pv1 = *(const uint4*)(vs + 8);
        }

        // softmax: P row per wave, strips sequential (DS in-order, v10-proven)
        short8 ap[2][2];
#pragma unroll
        for (int s = 0; s < 2; s++) {
#pragma unroll
            for (int f = 0; f < 4; f++) {
                uint2 mwf = *(const uint2*)&mrow[i * 64 + f * 16 + quad * 4];
                float p0 = __builtin_amdgcn_exp2f(st[s][f][0]);
                float p1 = __builtin_amdgcn_exp2f(st[s][f][1]);
                float p2 = __builtin_amdgcn_exp2f(st[s][f][2]);
                float p3 = __builtin_amdgcn_exp2f(st[s][f][3]);
                uint2 pw;
                pw.x = pack2bf_rhu(p0, p1) & mwf.x;
                pw.y = pack2bf_rhu(p2, p3) & mwf.y;
                *(uint2*)&prow[f * 16 + quad * 4] = pw;
            }
            asm volatile("s_waitcnt lgkmcnt(0)" ::: "memory");
            ap[s][0] = *(const short8*)&prow[quad * 8];
            ap[s][1] = *(const short8*)&prow[32 + quad * 8];
        }

        // PV: f-loop, bv[f] read ONCE and shared by both strips
        __builtin_amdgcn_s_setprio(1);
#pragma unroll
        for (int f = 0; f < 4; f++) {
            short8 bv0 = *(const short8*)&vT_s[g][f * 16 + l16][quad * 8];
            short8 bv1 = *(const short8*)&vT_s[g][f * 16 + l16][32 + quad * 8];
            o[0][f] = __builtin_amdgcn_mfma_f32_16x16x32_bf16(ap[0][0], bv0, o[0][f], 0, 0, 0);
            o[0][f] = __builtin_amdgcn_mfma_f32_16x16x32_bf16(ap[0][1], bv1, o[0][f], 0, 0, 0);
            o[1][f] = __builtin_amdgcn_mfma_f32_16x16x32_bf16(ap[1][0], bv0, o[1][f], 0, 0, 0);
            o[1][f] = __builtin_amdgcn_mfma_f32_16x16x32_bf16(ap[1][1], bv1, o[1][f], 0, 0, 0);
        }
        ol[0] = __builtin_amdgcn_mfma_f32_16x16x32_bf16(ap[0][0], ones, ol[0], 0, 0, 0);
        ol[0] = __builtin_amdgcn_mfma_f32_16x16x32_bf16(ap[0][1], ones, ol[0], 0, 0, 0);
        ol[1] = __builtin_amdgcn_mfma_f32_16x16x32_bf16(ap[1][0], ones, ol[1], 0, 0, 0);
        ol[1] = __builtin_amdgcn_mfma_f32_16x16x32_bf16(ap[1][1], ones, ol[1], 0, 0, 0);
        __builtin_amdgcn_s_setprio(0);

        __syncthreads();  // all waves done reading current tiles
        if (pf) {         // commit prefetched tile into the (single) buffers
            *(uint4*)&k_s[sg][sr][sc]      = pk0;
            *(uint4*)&k_s[sg][sr][sc + 8]  = pk1;
            *(uint4*)&vT_s[sg][sr][sc]     = pv0;
            *(uint4*)&vT_s[sg][sr][sc + 8] = pv1;
        }
    }
    // last iter's bottom barrier already ran -> K/V/P LDS is dead

    // combine: upper-half waves dump partial (O,l); lower-half adds (exact:
    // disjoint key sets under max-free softmax => simple addition)
    if (wave >= 4) {
        float* dst = comb + ((size_t)((wave - 4) * 64 + lane)) * 40;
#pragma unroll
        for (int s = 0; s < 2; s++)
#pragma unroll
            for (int f = 0; f < 4; f++)
                *(floatx4*)(dst + (s * 4 + f) * 4) = o[s][f];
        *(floatx4*)(dst + 32) = ol[0];
        *(floatx4*)(dst + 36) = ol[1];
    }
    __syncthreads();
    if (wave < 4) {
        const float* src = comb + ((size_t)(wave * 64 + lane)) * 40;
#pragma unroll
        for (int s = 0; s < 2; s++)
#pragma unroll
            for (int f = 0; f < 4; f++)
                o[s][f] += *(const floatx4*)(src + (s * 4 + f) * 4);
        ol[0] += *(const floatx4*)(src + 32);
        ol[1] += *(const floatx4*)(src + 36);

        // epilogue: ol[s][r] = L for q-row quad*4+r (identical at every lane)
#pragma unroll
        for (int s = 0; s < 2; s++) {
#pragma unroll
            for (int r = 0; r < 4; r++) {
                float inv = 1.0f / ol[s][r];
                size_t row = (size_t)(b * NQ + m0 + wave * 32 + s * 16 + quad * 4 + r);
#pragma unroll
                for (int f = 0; f < 4; f++) {
                    unsigned u = __builtin_bit_cast(unsigned, o[s][f][r] * inv) + 0x8000u;
                    x[row * DMODEL + h * HD + f * 16 + l16] = (unsigned short)(u >> 16);
                }
            }
        }
    }
}

extern "C" void kernel_launch(void* const* d_in, const int* in_sizes, int n_in,
                              void* d_out, int out_size, void* d_ws, size_t ws_size,
                              hipStream_t stream) {
    const float* q     = (const float*)d_in[0];
    const float* kv    = (const float*)d_in[1];
    const int*   mask  = (const int*)d_in[2];
    const float* Wq    = (const float*)d_in[3];
    const float* Wkv   = (const float*)d_in[4];
    const float* Wproj = (const float*)d_in[5];
    const float* bproj = (const float*)d_in[6];
    float* out = (float*)d_out;

    // ws layout, total <= proven 92,540,480 (R2)
    char* ws = (char*)d_ws;
    size_t o = 0;
    o += 256;  // (reserved)
    unsigned short* maskb  = (unsigned short*)(ws + o); o += 65536;  // 32KB used
    unsigned short* Qb     = (unsigned short*)(ws + o); o += (size_t)BB * NQ * DMODEL * 2;   // 8 MB
    unsigned short* Kb     = (unsigned short*)(ws + o); o += (size_t)BB * NKV * DMODEL * 2;  // 32 MB
    unsigned short* VTb    = (unsigned short*)(ws + o); o += (size_t)BB * NKV * DMODEL * 2;  // 32 MB
    unsigned short* WprojT = (unsigned short*)(ws + o); o += (size_t)DMODEL * DMODEL * 2;    // 2 MB
    unsigned short* xb     = (unsigned short*)(ws + o); // attn output (bf16)
    o += (size_t)BB * NQ * DMODEL * 2;                  // 8 MB
    unsigned short* WqT    = (unsigned short*)(ws + o); o += (size_t)DMODEL * DMODEL * 2;     // 2 MB
    unsigned short* WkvT   = (unsigned short*)(ws + o); o += (size_t)DMODEL * 2 * DMODEL * 2; // 4 MB

    hipLaunchKernelGGL(maskprep3, dim3(1), dim3(1024), 0, stream, mask, maskb);
    hipLaunchKernelGGL(transpose_cast3, dim3(32, DMODEL / 64, 3), dim3(256), 0, stream,
                       Wq, Wkv, Wproj, WqT, WkvT, WprojT);

    // Qb = bf16((q @ Wq) * hd^-0.5 * log2(e)); A staged fp32->bf16 in-kernel
    hipLaunchKernelGGL((gemm_mfma<0, 1>), dim3(DMODEL / 128, BB * NQ / 128), dim3(256), 16384, stream,
                       (const unsigned short*)nullptr, q, WqT, (const float*)nullptr,
                       Qb, (unsigned short*)nullptr, (float*)nullptr,
                       BB * NQ, DMODEL, DMODEL, 0.125f * 1.44269504f, 0);

    // kv projection: ONE launch, all 16384 rows, A staged fp32->bf16 in-kernel
    hipLaunchKernelGGL((gemm_mfma<1, 1>), dim3(2 * DMODEL / 128, BB * NKV / 128), dim3(256), 36864, stream,
                       (const unsigned short*)nullptr, kv, WkvT, (const float*)nullptr,
                       Kb, VTb, (float*)nullptr,
                       BB * NKV, 2 * DMODEL, DMODEL, 1.0f, 0);

    // fused flash attention v11 -> xb (bf16)
    hipLaunchKernelGGL(attn_mfma11, dim3(NQ / 128, BB * NH), dim3(512), 0, stream,
                       Qb, Kb, VTb, maskb, xb);

    // out = xb @ Wproj + bproj (fp32)
    hipLaunchKernelGGL((gemm_mfma<2, 0>), dim3(DMODEL / 128, BB * NQ / 128), dim3(256), 16384, stream,
                       xb, (const float*)nullptr, WprojT, bproj,
                       (unsigned short*)nullptr, (unsigned short*)nullptr, out,
                       BB * NQ, DMODEL, DMODEL, 1.0f, 0);
}

// Round 12
// 387.379 us; speedup vs baseline: 1.0736x; 1.0736x over previous
//
#include <hip/hip_runtime.h>
#include <hip/hip_bf16.h>
#include <math.h>

#define BB 4
#define NQ 1024
#define NKV 4096
#define DMODEL 1024
#define NH 16
#define HD 64

typedef __attribute__((ext_vector_type(8))) short short8;
typedef __attribute__((ext_vector_type(4))) float floatx4;

__device__ __forceinline__ unsigned short f2bf(float f) {
    __hip_bfloat16 b = __float2bfloat16(f);
    return *reinterpret_cast<unsigned short*>(&b);
}

// pack two known-finite positive floats to bf16x2, round-half-up (proven v4-v11)
__device__ __forceinline__ unsigned int pack2bf_rhu(float a, float b) {
    unsigned ua = __builtin_bit_cast(unsigned, a) + 0x8000u;
    unsigned ub = __builtin_bit_cast(unsigned, b) + 0x8000u;
    return (ua >> 16) | (ub & 0xffff0000u);
}

// async global->LDS DMA, 16B/lane. Dest = wave-uniform base + lane*16.
__device__ __forceinline__ void gl_lds16(void* lds, const void* g) {
    __builtin_amdgcn_global_load_lds(
        (const __attribute__((address_space(1))) unsigned int*)g,
        (__attribute__((address_space(3))) unsigned int*)lds, 16, 0, 0);
}

__device__ __forceinline__ short8 cvt16(const float4& a, const float4& b) {
    short8 v;
    v[0] = (short)f2bf(a.x); v[1] = (short)f2bf(a.y);
    v[2] = (short)f2bf(a.z); v[3] = (short)f2bf(a.w);
    v[4] = (short)f2bf(b.x); v[5] = (short)f2bf(b.y);
    v[6] = (short)f2bf(b.z); v[7] = (short)f2bf(b.w);
    return v;
}

// ---------------- mask: detect format + expand to AND-halfwords ----------------
__global__ __launch_bounds__(1024) void maskprep3(const int* __restrict__ mask,
                                                  unsigned short* __restrict__ maskb) {
    __shared__ int s;
    if (threadIdx.x == 0) s = 0;
    __syncthreads();
    int local = 0;
    for (int i = threadIdx.x; i < 4096; i += 1024)
        if (((const unsigned*)mask)[i] > 1u) local = 1;
    if (local) atomicOr(&s, 1);
    __syncthreads();
    const bool bytes = (s != 0);
    for (int i = threadIdx.x; i < BB * NKV; i += 1024) {
        bool m = bytes ? (((const unsigned char*)mask)[i] != 0) : (mask[i] != 0);
        maskb[i] = m ? (unsigned short)0 : (unsigned short)0xFFFFu;
    }
}

// ---------------- all 3 weight transposes in ONE launch -------------------------
__global__ __launch_bounds__(256) void transpose_cast3(
    const float* __restrict__ Wq, const float* __restrict__ Wkv,
    const float* __restrict__ Wproj,
    unsigned short* __restrict__ WqT, unsigned short* __restrict__ WkvT,
    unsigned short* __restrict__ WprojT)
{
    const float* src; unsigned short* dst; int N;
    if (blockIdx.z == 0)      { src = Wq;    dst = WqT;    N = DMODEL; }
    else if (blockIdx.z == 1) { src = Wkv;   dst = WkvT;   N = 2 * DMODEL; }
    else                      { src = Wproj; dst = WprojT; N = DMODEL; }
    if ((int)blockIdx.x * 64 >= N) return;
    const int K = DMODEL;
    __shared__ unsigned short t[64][72];
    int r0 = blockIdx.y * 64, c0 = blockIdx.x * 64;
    int tid = threadIdx.x;
#pragma unroll
    for (int i = 0; i < 4; i++) {
        int r = i * 16 + (tid >> 4), c = (tid & 15) * 4;
        float4 v = *(const float4*)&src[(size_t)(r0 + r) * N + c0 + c];
        t[c + 0][r] = f2bf(v.x); t[c + 1][r] = f2bf(v.y);
        t[c + 2][r] = f2bf(v.z); t[c + 3][r] = f2bf(v.w);
    }
    __syncthreads();
#pragma unroll
    for (int i = 0; i < 2; i++) {
        int rr = i * 32 + (tid >> 3), cc = (tid & 7) * 8;
        *(uint4*)&dst[(size_t)(c0 + rr) * K + r0 + cc] = *(uint4*)&t[rr][cc];
    }
}

// ---------------- bf16 MFMA GEMM (R12) ------------------------------------------
// R11's one-barrier double-buffer pipeline FAILED (absmax 2e-2, race not
// identifiable on paper) -> abandoned. R12 pipelines with ONLY in-session-
// proven skeletons:
//  * AF32: attn_mfma11's commit->sync1->prefetch->compute->sync2 scheme.
//    A fp32 regs prefetched after sync1, consumed at NEXT iter's commit
//    (cover = compute+sync2, exactly attn's). As is a SINGLE 8KB buffer:
//    commit-write vs read separated by sync1; read vs next commit by sync2.
//    B via gl_lds16 into a DUAL buffer: issued after sync1(ki), read after
//    sync1(ki+1) — TWO barriers between issue and read (stricter than R7's
//    proven one-barrier DMA pattern). LDS 24KB.
//  * !AF32 (out-proj): byte-exact R7 two-barrier single-buffer structure.
// Slot mapping, cvt16 numerics, epilogues, XCD swizzle: R10-proven.
template <int EPI, int AF32>
__global__ __launch_bounds__(256, 2) void gemm_mfma(
    const unsigned short* __restrict__ A,
    const float* __restrict__ A32,
    const unsigned short* __restrict__ Bt,
    const float* __restrict__ bias,
    unsigned short* __restrict__ o16,
    unsigned short* __restrict__ oT,
    float* __restrict__ o32,
    int M, int N, int K, float alpha, int m_out_base)
{
    extern __shared__ char smem[];
    // AF32 layout: As = smem (8KB single) ; Bs[2] = +8192 / +16384 (24KB)
    // !AF32 layout: As = smem (8KB) ; Bs = +8192 (16KB)
    const int tid = threadIdx.x;
    const int wave = tid >> 6, lane = tid & 63;
    const int quad = lane >> 4, l16 = lane & 15;
    const int wm = wave >> 1, wn = wave & 1;

    // bijective XCD swizzle (nwg % 8 == 0 for all our grids; R10-proven)
    const int nwg = gridDim.x * gridDim.y;
    const int lid0 = blockIdx.y * gridDim.x + blockIdx.x;
    const int lid = (lid0 & 7) * (nwg >> 3) + (lid0 >> 3);
    const int bx = lid % gridDim.x, by = lid / gridDim.x;
    const int m0 = by * 128, n0 = bx * 128;

    const int c0 = wave * 64 + lane, c1 = c0 + 256;
    const int r0s = c0 >> 2, cc0 = (c0 & 3) ^ ((r0s >> 2) & 3);
    const int r1s = c1 >> 2, cc1 = (c1 & 3) ^ ((r1s >> 2) & 3);
    const unsigned short* bg0 = Bt + (size_t)(n0 + r0s) * K + cc0 * 8;
    const unsigned short* bg1 = Bt + (size_t)(n0 + r1s) * K + cc1 * 8;

    const int woff0 = (wave * 64) * 16;          // DMA dest (+ lane*16 by HW)
    const int woff1 = (256 + wave * 64) * 16;
    const int loff0 = c0 * 16, loff1 = c1 * 16;  // per-lane ds_write dest

    int achk[4], bchk[4];
#pragma unroll
    for (int i = 0; i < 4; i++) {
        int ra = wm * 64 + i * 16 + l16;
        achk[i] = ra * 4 + (quad ^ ((ra >> 2) & 3));
        int rb = wn * 64 + i * 16 + l16;
        bchk[i] = rb * 4 + (quad ^ ((rb >> 2) & 3));
    }

    floatx4 acc[4][4];
#pragma unroll
    for (int i = 0; i < 4; i++)
#pragma unroll
        for (int j = 0; j < 4; j++) acc[i][j] = (floatx4)0.0f;

    const int nk = K >> 5;   // K/32 tiles (K=1024 -> 32)

    if constexpr (AF32) {
        const float* ag0f = A32 + (size_t)(m0 + r0s) * K + cc0 * 8;
        const float* ag1f = A32 + (size_t)(m0 + r1s) * K + cc1 * 8;
        // prologue: A tile0 -> regs; B tile0 -> Bs[0] via DMA
        float4 pa0 = *(const float4*)(ag0f),     pa1 = *(const float4*)(ag0f + 4);
        float4 pa2 = *(const float4*)(ag1f),     pa3 = *(const float4*)(ag1f + 4);
        gl_lds16(smem + 8192 + woff0, bg0);
        gl_lds16(smem + 8192 + woff1, bg1);

        for (int ki = 0; ki < nk; ki++) {
            // commit A(ki) into the single As buffer (attn-proven skeleton)
            *(short8*)(smem + loff0) = cvt16(pa0, pa1);
            *(short8*)(smem + loff1) = cvt16(pa2, pa3);
            __syncthreads();   // sync1: commit + B(ki) DMA visible to all waves

            const char* rbB = smem + 8192 + (ki & 1) * 8192;
            if (ki + 1 < nk) {  // prefetch next A to regs; DMA next B to Bs^1
                const int e1 = (ki + 1) * 32;
                pa0 = *(const float4*)(ag0f + e1);
                pa1 = *(const float4*)(ag0f + e1 + 4);
                pa2 = *(const float4*)(ag1f + e1);
                pa3 = *(const float4*)(ag1f + e1 + 4);
                char* wbB = smem + 8192 + ((ki + 1) & 1) * 8192;
                gl_lds16(wbB + woff0, bg0 + e1);
                gl_lds16(wbB + woff1, bg1 + e1);
            }

            short8 af[4], bfr[4];
#pragma unroll
            for (int i = 0; i < 4; i++) af[i] = *(const short8*)(smem + achk[i] * 16);
#pragma unroll
            for (int j = 0; j < 4; j++) bfr[j] = *(const short8*)(rbB + bchk[j] * 16);
#pragma unroll
            for (int i = 0; i < 4; i++)
#pragma unroll
                for (int j = 0; j < 4; j++)
                    acc[i][j] = __builtin_amdgcn_mfma_f32_16x16x32_bf16(
                        af[i], bfr[j], acc[i][j], 0, 0, 0);

            __syncthreads();   // sync2: As/Bs reads done; next commit may write
        }
    } else {
        // byte-exact R7 structure: two barriers, single buffer, all-DMA
        const unsigned short* ag0 = A + (size_t)(m0 + r0s) * K + cc0 * 8;
        const unsigned short* ag1 = A + (size_t)(m0 + r1s) * K + cc1 * 8;
        for (int kt = 0; kt < K; kt += 32) {
            __syncthreads();
            gl_lds16(smem + woff0, ag0 + kt);
            gl_lds16(smem + woff1, ag1 + kt);
            gl_lds16(smem + 8192 + woff0, bg0 + kt);
            gl_lds16(smem + 8192 + woff1, bg1 + kt);
            __syncthreads();
            short8 af[4], bfr[4];
#pragma unroll
            for (int i = 0; i < 4; i++)
                af[i] = *(const short8*)(smem + achk[i] * 16);
#pragma unroll
            for (int j = 0; j < 4; j++)
                bfr[j] = *(const short8*)(smem + 8192 + bchk[j] * 16);
#pragma unroll
            for (int i = 0; i < 4; i++)
#pragma unroll
                for (int j = 0; j < 4; j++)
                    acc[i][j] = __builtin_amdgcn_mfma_f32_16x16x32_bf16(
                        af[i], bfr[j], acc[i][j], 0, 0, 0);
        }
    }

    const int rowbase = m0 + wm * 64;
    const int colbase = n0 + wn * 64;
    if (EPI == 0) {
#pragma unroll
        for (int i = 0; i < 4; i++)
#pragma unroll
            for (int r = 0; r < 4; r++) {
                size_t row = (size_t)(rowbase + i * 16 + quad * 4 + r);
#pragma unroll
                for (int j = 0; j < 4; j++)
                    o16[row * N + colbase + j * 16 + l16] =
                        f2bf(acc[i][j][r] * alpha);
            }
    } else if (EPI == 2) {
        float bv[4];
#pragma unroll
        for (int j = 0; j < 4; j++) bv[j] = bias[colbase + j * 16 + l16];
#pragma unroll
        for (int i = 0; i < 4; i++)
#pragma unroll
            for (int r = 0; r < 4; r++) {
                size_t row = (size_t)(rowbase + i * 16 + quad * 4 + r);
#pragma unroll
                for (int j = 0; j < 4; j++)
                    o32[row * N + colbase + j * 16 + l16] = acc[i][j][r] + bv[j];
            }
    } else {  // EPI == 1: N=2048; cols<1024 -> Kb natural, cols>=1024 -> VTb^T
        if (n0 < DMODEL) {
#pragma unroll
            for (int i = 0; i < 4; i++)
#pragma unroll
                for (int r = 0; r < 4; r++) {
                    int gm = m_out_base + rowbase + i * 16 + quad * 4 + r;
                    int b = gm >> 12, key = gm & (NKV - 1);
                    size_t row = (size_t)(b * NKV + key);
#pragma unroll
                    for (int j = 0; j < 4; j++)
                        o16[row * DMODEL + colbase + j * 16 + l16] =
                            f2bf(acc[i][j][r]);
                }
        } else {
            __syncthreads();
            unsigned short (*scr)[72] =
                (unsigned short(*)[72])(smem + wave * 64 * 72 * 2);
#pragma unroll
            for (int i = 0; i < 4; i++)
#pragma unroll
                for (int j = 0; j < 4; j++)
#pragma unroll
                    for (int r = 0; r < 4; r++)
                        scr[j * 16 + l16][i * 16 + quad * 4 + r] =
                            f2bf(acc[i][j][r]);
            __syncthreads();
            int gmb = m_out_base + rowbase;
            int b = gmb >> 12, key0 = gmb & (NKV - 1);
            int d0 = colbase - DMODEL;
#pragma unroll
            for (int p = 0; p < 8; p++) {
                int rr = p * 8 + (lane >> 3), ch = lane & 7;
                *(uint4*)&oT[((size_t)(b * DMODEL + d0 + rr)) * NKV + key0 + ch * 8] =
                    *(uint4*)&scr[rr][ch * 8];
            }
        }
    }
}

// ---------------- fused flash attention v11: KV-split, register-lean ------------
// (unchanged from R7 — PASS @ 102.7us)
__global__ __launch_bounds__(512, 2) void attn_mfma11(
    const unsigned short* __restrict__ Qb,   // (B,NQ,D) bf16, scaled
    const unsigned short* __restrict__ Kb,   // (B,NKV,D) bf16
    const unsigned short* __restrict__ VTb,  // (B,D,NKV) bf16
    const unsigned short* __restrict__ maskb,// (B,NKV) 0xFFFF keep / 0 masked
    unsigned short* __restrict__ x)          // (B,NQ,D) bf16
{
    const int lid = blockIdx.y * gridDim.x + blockIdx.x;  // [0,512)
    const int xcd = lid & 7, slot = lid >> 3;             // slot in [0,64)
    const int bh = xcd * 8 + (slot & 7);    // 8 q-tiles of one (b,h) per XCD
    const int b = bh >> 4, h = bh & 15;
    const int m0 = (slot >> 3) * 128;
    const int tid = threadIdx.x;
    const int wave = tid >> 6, lane = tid & 63;
    const int quad = lane >> 4, l16 = lane & 15;
    const int sp = wave & 3;   // strip-pair: rows m0+sp*32 .. +32
    const int g  = wave >> 2;  // KV half: tiles g*32 .. g*32+31

    __shared__ __align__(16) char smem[55296];
    unsigned short (*k_s)[64][72]  = (unsigned short (*)[64][72])(smem);          // [2]
    unsigned short (*vT_s)[64][72] = (unsigned short (*)[64][72])(smem + 18432);  // [2]
    unsigned short (*qp_s)[16][72] = (unsigned short (*)[16][72])(smem + 36864);  // [8]
    float* comb = (float*)smem;  // epilogue reuse: 256 lanes x 40 floats = 40KB

    const unsigned short* Kbase = Kb + ((size_t)b * NKV) * DMODEL + h * HD;
    const unsigned short* Vbase = VTb + ((size_t)(b * DMODEL + h * HD)) * NKV;

    // staging: 256-thread group sg stages stream sg; 2 uint4 per array/thread
    const int sg  = tid >> 8;           // 0/1 = which stream this thread stages
    const int t8  = tid & 255;
    const int sr  = t8 >> 2;            // row 0..63
    const int sc  = (t8 & 3) * 16;      // col 0,16,32,48
    const int key00 = sg * 2048;        // stream's first key

    // prologue: stage tile (sg*32) of each stream
    {
        const unsigned short* ks = Kbase + (size_t)(key00 + sr) * DMODEL + sc;
        uint4 a0 = *(const uint4*)ks, a1 = *(const uint4*)(ks + 8);
        const unsigned short* vs = Vbase + (size_t)sr * NKV + key00 + sc;
        uint4 b0 = *(const uint4*)vs, b1 = *(const uint4*)(vs + 8);
        *(uint4*)&k_s[sg][sr][sc]      = a0;
        *(uint4*)&k_s[sg][sr][sc + 8]  = a1;
        *(uint4*)&vT_s[sg][sr][sc]     = b0;
        *(uint4*)&vT_s[sg][sr][sc + 8] = b1;
    }

    // Q B-frags for both strips of this wave's pair (direct from global)
    short8 bq[2][2];
#pragma unroll
    for (int s = 0; s < 2; s++) {
        const unsigned short* qsrc =
            Qb + ((size_t)(b * NQ + m0 + sp * 32 + s * 16 + l16)) * DMODEL +
            h * HD + quad * 8;
        bq[s][0] = *(const short8*)qsrc;
        bq[s][1] = *(const short8*)(qsrc + 32);
    }

    const unsigned short* mrow = maskb + b * NKV + g * 2048;
    unsigned short* prow = &qp_s[wave][l16][0];

    short8 ones;
#pragma unroll
    for (int e = 0; e < 8; e++) ones[e] = (short)0x3F80;  // bf16 1.0

    floatx4 o[2][4], ol[2];
#pragma unroll
    for (int s = 0; s < 2; s++) {
#pragma unroll
        for (int f = 0; f < 4; f++) o[s][f] = (floatx4)0.0f;
        ol[s] = (floatx4)0.0f;
    }

    __syncthreads();  // prologue staging visible

    for (int i = 0; i < 32; i++) {
        if (i) __syncthreads();  // commits from prev iter visible
        const bool pf = (i < 31);
        const int nn = key00 + (i + 1) * 64;

        // K prefetch issued before QK (8 VGPRs live through QK phase)
        uint4 pk0, pk1;
        if (pf) {
            const unsigned short* ks = Kbase + (size_t)(nn + sr) * DMODEL + sc;
            pk0 = *(const uint4*)ks; pk1 = *(const uint4*)(ks + 8);
        }

        // QK: f-loop, ak[f] read ONCE and shared by both strips
        floatx4 st[2][4];
        __builtin_amdgcn_s_setprio(1);
#pragma unroll
        for (int f = 0; f < 4; f++) {
            short8 ak0 = *(const short8*)&k_s[g][f * 16 + l16][quad * 8];
            short8 ak1 = *(const short8*)&k_s[g][f * 16 + l16][32 + quad * 8];
            floatx4 t0 = (floatx4)0.0f, t1 = (floatx4)0.0f;
            t0 = __builtin_amdgcn_mfma_f32_16x16x32_bf16(ak0, bq[0][0], t0, 0, 0, 0);
            t0 = __builtin_amdgcn_mfma_f32_16x16x32_bf16(ak1, bq[0][1], t0, 0, 0, 0);
            t1 = __builtin_amdgcn_mfma_f32_16x16x32_bf16(ak0, bq[1][0], t1, 0, 0, 0);
            t1 = __builtin_amdgcn_mfma_f32_16x16x32_bf16(ak1, bq[1][1], t1, 0, 0, 0);
            st[0][f] = t0; st[1][f] = t1;
        }
        __builtin_amdgcn_s_setprio(0);

        // V prefetch issued after QK (8 VGPRs live through softmax+PV)
        uint4 pv0, pv1;
        if (pf) {
            const unsigned short* vs = Vbase + (size_t)sr * NKV + nn + sc;
            pv0 = *(const uint4*)vs; pv1 = *(const uint4*)(vs + 8);
        }

        // softmax: P row per wave, strips sequential (DS in-order, v10-proven)
        short8 ap[2][2];
#pragma unroll
        for (int s = 0; s < 2; s++) {
#pragma unroll
            for (int f = 0; f < 4; f++) {
                uint2 mwf = *(const uint2*)&mrow[i * 64 + f * 16 + quad * 4];
                float p0 = __builtin_amdgcn_exp2f(st[s][f][0]);
                float p1 = __builtin_amdgcn_exp2f(st[s][f][1]);
                float p2 = __builtin_amdgcn_exp2f(st[s][f][2]);
                float p3 = __builtin_amdgcn_exp2f(st[s][f][3]);
                uint2 pw;
                pw.x = pack2bf_rhu(p0, p1) & mwf.x;
                pw.y = pack2bf_rhu(p2, p3) & mwf.y;
                *(uint2*)&prow[f * 16 + quad * 4] = pw;
            }
            asm volatile("s_waitcnt lgkmcnt(0)" ::: "memory");
            ap[s][0] = *(const short8*)&prow[quad * 8];
            ap[s][1] = *(const short8*)&prow[32 + quad * 8];
        }

        // PV: f-loop, bv[f] read ONCE and shared by both strips
        __builtin_amdgcn_s_setprio(1);
#pragma unroll
        for (int f = 0; f < 4; f++) {
            short8 bv0 = *(const short8*)&vT_s[g][f * 16 + l16][quad * 8];
            short8 bv1 = *(const short8*)&vT_s[g][f * 16 + l16][32 + quad * 8];
            o[0][f] = __builtin_amdgcn_mfma_f32_16x16x32_bf16(ap[0][0], bv0, o[0][f], 0, 0, 0);
            o[0][f] = __builtin_amdgcn_mfma_f32_16x16x32_bf16(ap[0][1], bv1, o[0][f], 0, 0, 0);
            o[1][f] = __builtin_amdgcn_mfma_f32_16x16x32_bf16(ap[1][0], bv0, o[1][f], 0, 0, 0);
            o[1][f] = __builtin_amdgcn_mfma_f32_16x16x32_bf16(ap[1][1], bv1, o[1][f], 0, 0, 0);
        }
        ol[0] = __builtin_amdgcn_mfma_f32_16x16x32_bf16(ap[0][0], ones, ol[0], 0, 0, 0);
        ol[0] = __builtin_amdgcn_mfma_f32_16x16x32_bf16(ap[0][1], ones, ol[0], 0, 0, 0);
        ol[1] = __builtin_amdgcn_mfma_f32_16x16x32_bf16(ap[1][0], ones, ol[1], 0, 0, 0);
        ol[1] = __builtin_amdgcn_mfma_f32_16x16x32_bf16(ap[1][1], ones, ol[1], 0, 0, 0);
        __builtin_amdgcn_s_setprio(0);

        __syncthreads();  // all waves done reading current tiles
        if (pf) {         // commit prefetched tile into the (single) buffers
            *(uint4*)&k_s[sg][sr][sc]      = pk0;
            *(uint4*)&k_s[sg][sr][sc + 8]  = pk1;
            *(uint4*)&vT_s[sg][sr][sc]     = pv0;
            *(uint4*)&vT_s[sg][sr][sc + 8] = pv1;
        }
    }
    // last iter's bottom barrier already ran -> K/V/P LDS is dead

    // combine: upper-half waves dump partial (O,l); lower-half adds (exact:
    // disjoint key sets under max-free softmax => simple addition)
    if (wave >= 4) {
        float* dst = comb + ((size_t)((wave - 4) * 64 + lane)) * 40;
#pragma unroll
        for (int s = 0; s < 2; s++)
#pragma unroll
            for (int f = 0; f < 4; f++)
                *(floatx4*)(dst + (s * 4 + f) * 4) = o[s][f];
        *(floatx4*)(dst + 32) = ol[0];
        *(floatx4*)(dst + 36) = ol[1];
    }
    __syncthreads();
    if (wave < 4) {
        const float* src = comb + ((size_t)(wave * 64 + lane)) * 40;
#pragma unroll
        for (int s = 0; s < 2; s++)
#pragma unroll
            for (int f = 0; f < 4; f++)
                o[s][f] += *(const floatx4*)(src + (s * 4 + f) * 4);
        ol[0] += *(const floatx4*)(src + 32);
        ol[1] += *(const floatx4*)(src + 36);

        // epilogue: ol[s][r] = L for q-row quad*4+r (identical at every lane)
#pragma unroll
        for (int s = 0; s < 2; s++) {
#pragma unroll
            for (int r = 0; r < 4; r++) {
                float inv = 1.0f / ol[s][r];
                size_t row = (size_t)(b * NQ + m0 + wave * 32 + s * 16 + quad * 4 + r);
#pragma unroll
                for (int f = 0; f < 4; f++) {
                    unsigned u = __builtin_bit_cast(unsigned, o[s][f][r] * inv) + 0x8000u;
                    x[row * DMODEL + h * HD + f * 16 + l16] = (unsigned short)(u >> 16);
                }
            }
        }
    }
}

extern "C" void kernel_launch(void* const* d_in, const int* in_sizes, int n_in,
                              void* d_out, int out_size, void* d_ws, size_t ws_size,
                              hipStream_t stream) {
    const float* q     = (const float*)d_in[0];
    const float* kv    = (const float*)d_in[1];
    const int*   mask  = (const int*)d_in[2];
    const float* Wq    = (const float*)d_in[3];
    const float* Wkv   = (const float*)d_in[4];
    const float* Wproj = (const float*)d_in[5];
    const float* bproj = (const float*)d_in[6];
    float* out = (float*)d_out;

    // ws layout, total <= proven 92,540,480 (R2)
    char* ws = (char*)d_ws;
    size_t o = 0;
    o += 256;  // (reserved)
    unsigned short* maskb  = (unsigned short*)(ws + o); o += 65536;  // 32KB used
    unsigned short* Qb     = (unsigned short*)(ws + o); o += (size_t)BB * NQ * DMODEL * 2;   // 8 MB
    unsigned short* Kb     = (unsigned short*)(ws + o); o += (size_t)BB * NKV * DMODEL * 2;  // 32 MB
    unsigned short* VTb    = (unsigned short*)(ws + o); o += (size_t)BB * NKV * DMODEL * 2;  // 32 MB
    unsigned short* WprojT = (unsigned short*)(ws + o); o += (size_t)DMODEL * DMODEL * 2;    // 2 MB
    unsigned short* xb     = (unsigned short*)(ws + o); // attn output (bf16)
    o += (size_t)BB * NQ * DMODEL * 2;                  // 8 MB
    unsigned short* WqT    = (unsigned short*)(ws + o); o += (size_t)DMODEL * DMODEL * 2;     // 2 MB
    unsigned short* WkvT   = (unsigned short*)(ws + o); o += (size_t)DMODEL * 2 * DMODEL * 2; // 4 MB

    hipLaunchKernelGGL(maskprep3, dim3(1), dim3(1024), 0, stream, mask, maskb);
    hipLaunchKernelGGL(transpose_cast3, dim3(32, DMODEL / 64, 3), dim3(256), 0, stream,
                       Wq, Wkv, Wproj, WqT, WkvT, WprojT);

    // Qb = bf16((q @ Wq) * hd^-0.5 * log2(e)); A staged fp32->bf16 in-kernel
    hipLaunchKernelGGL((gemm_mfma<0, 1>), dim3(DMODEL / 128, BB * NQ / 128), dim3(256), 24576, stream,
                       (const unsigned short*)nullptr, q, WqT, (const float*)nullptr,
                       Qb, (unsigned short*)nullptr, (float*)nullptr,
                       BB * NQ, DMODEL, DMODEL, 0.125f * 1.44269504f, 0);

    // kv projection: ONE launch, all 16384 rows, A staged fp32->bf16 in-kernel
    hipLaunchKernelGGL((gemm_mfma<1, 1>), dim3(2 * DMODEL / 128, BB * NKV / 128), dim3(256), 36864, stream,
                       (const unsigned short*)nullptr, kv, WkvT, (const float*)nullptr,
                       Kb, VTb, (float*)nullptr,
                       BB * NKV, 2 * DMODEL, DMODEL, 1.0f, 0);

    // fused flash attention v11 -> xb (bf16)
    hipLaunchKernelGGL(attn_mfma11, dim3(NQ / 128, BB * NH), dim3(512), 0, stream,
                       Qb, Kb, VTb, maskb, xb);

    // out = xb @ Wproj + bproj (fp32)
    hipLaunchKernelGGL((gemm_mfma<2, 0>), dim3(DMODEL / 128, BB * NQ / 128), dim3(256), 16384, stream,
                       xb, (const float*)nullptr, WprojT, bproj,
                       (unsigned short*)nullptr, (unsigned short*)nullptr, out,
                       BB * NQ, DMODEL, DMODEL, 1.0f, 0);
}